// Round 2
// baseline (924.410 us; speedup 1.0000x reference)
//
#include <hip/hip_runtime.h>

#define BB 1024
#define TT 128
#define NBLK 256

using bf16   = __bf16;
using bf16x8 = __attribute__((ext_vector_type(8))) bf16;
using bf16x4 = __attribute__((ext_vector_type(4))) bf16;
using f32x4  = __attribute__((ext_vector_type(4))) float;

__device__ __forceinline__ float fsig(float x) {
  return __builtin_amdgcn_rcpf(1.f + __expf(-x));
}
__device__ __forceinline__ float ftanh(float x) {
  return 2.f * __builtin_amdgcn_rcpf(1.f + __expf(-2.f * x)) - 1.f;
}

// ---- coherent (cross-XCD, IF$-served) load/store helpers -------------------
__device__ __forceinline__ void st_u32_coh(unsigned* p, unsigned v) {
  __hip_atomic_store(p, v, __ATOMIC_RELAXED, __HIP_MEMORY_SCOPE_AGENT);
}
__device__ __forceinline__ unsigned ld_u32_coh(const unsigned* p) {
  return __hip_atomic_load((unsigned*)p, __ATOMIC_RELAXED, __HIP_MEMORY_SCOPE_AGENT);
}
__device__ __forceinline__ float ld_f32_coh(const float* p) {
  return __hip_atomic_load((float*)p, __ATOMIC_RELAXED, __HIP_MEMORY_SCOPE_AGENT);
}
__device__ __forceinline__ void st_f32_coh(float* p, float v) {
  __hip_atomic_store(p, v, __ATOMIC_RELAXED, __HIP_MEMORY_SCOPE_AGENT);
}
__device__ __forceinline__ void st_u16_coh(unsigned short* p, unsigned short v) {
  __hip_atomic_store(p, v, __ATOMIC_RELAXED, __HIP_MEMORY_SCOPE_AGENT);
}
__device__ __forceinline__ bf16x8 ld_bf16x8_coh(const bf16* p) {
  union { unsigned long long u[2]; bf16x8 v; } c;
  c.u[0] = __hip_atomic_load((unsigned long long*)p, __ATOMIC_RELAXED, __HIP_MEMORY_SCOPE_AGENT);
  c.u[1] = __hip_atomic_load((unsigned long long*)(p + 4), __ATOMIC_RELAXED, __HIP_MEMORY_SCOPE_AGENT);
  return c.v;
}

// ---------------------------------------------------------------------------
// prep (single launch): x f32 [B,T,256] -> bf16 [T,row'(b),256] (2048 blocks);
// WMg (512 blocks, block-local softmax); FM; bias; G0; zero slots
// ---------------------------------------------------------------------------
__global__ void prep(const float* __restrict__ x, const float* __restrict__ mem,
                     const float* __restrict__ b_ih, const float* __restrict__ b_hh,
                     const float* __restrict__ rv0, const float* __restrict__ W_ih,
                     const float* __restrict__ fc_w,
                     bf16* __restrict__ x_bf, bf16* __restrict__ WMg,
                     float* __restrict__ bias, float* __restrict__ G0,
                     float* __restrict__ FM, unsigned* __restrict__ slots) {
  const int bid = blockIdx.x, tid = threadIdx.x;
  if (bid < 2048) {
    const int lane = tid & 63, wv = tid >> 6;
    const int wg = bid * 4 + wv;  // 0..8191
#pragma unroll 4
    for (int r = 0; r < 16; ++r) {
      int rid = wg + r * 8192;            // rid = b*T + t
      int b = rid >> 7, t = rid & 127;
      int rowp = ((b >> 4) & 15) * 64 + (b >> 8) * 16 + (b & 15);
      const float4 v = *(const float4*)(x + (size_t)rid * 256 + lane * 4);
      bf16x4 o;
      o[0] = (bf16)v.x; o[1] = (bf16)v.y; o[2] = (bf16)v.z; o[3] = (bf16)v.w;
      *(bf16x4*)(x_bf + ((size_t)t * BB + rowp) * 256 + lane * 4) = o;
    }
  } else if (bid < 2560) {
    // WM[g][r*128+n] = sum_m W_ih[g][256+r*128+m]*mem_sm[m][n]
    __shared__ float sSM[16384];
    const int g = bid - 2048;
    if (tid < 128) {
      float mx = -1e30f;
      for (int m = 0; m < 128; ++m) mx = fmaxf(mx, mem[m * 128 + tid]);
      float s = 0.f;
      for (int m = 0; m < 128; ++m) s += __expf(mem[m * 128 + tid] - mx);
      float inv = 1.f / s;
      for (int m = 0; m < 128; ++m) sSM[m * 128 + tid] = __expf(mem[m * 128 + tid] - mx) * inv;
    }
    __syncthreads();
    const int r = tid >> 6, n0 = (tid & 63) * 2;
    const float* wr = W_ih + (size_t)g * 768 + 256 + r * 128;
    float a0 = 0.f, a1 = 0.f;
#pragma unroll 4
    for (int m = 0; m < 128; ++m) {
      float2 ms = *(const float2*)(sSM + m * 128 + n0);
      float w = wr[m];
      a0 += w * ms.x;
      a1 += w * ms.y;
    }
    union { bf16 h[2]; unsigned u; } pk;
    pk.h[0] = (bf16)a0; pk.h[1] = (bf16)a1;
    *(unsigned*)(WMg + (size_t)g * 512 + r * 128 + n0) = pk.u;
  } else if (bid == 2560) {
    __shared__ float sSM[16384];
    if (tid < 128) {
      float mx = -1e30f;
      for (int m = 0; m < 128; ++m) mx = fmaxf(mx, mem[m * 128 + tid]);
      float s = 0.f;
      for (int m = 0; m < 128; ++m) s += __expf(mem[m * 128 + tid] - mx);
      float inv = 1.f / s;
      for (int m = 0; m < 128; ++m) sSM[m * 128 + tid] = __expf(mem[m * 128 + tid] - mx) * inv;
    }
    __syncthreads();
    for (int sub = tid; sub < 2 * 512; sub += 256) {
      int o = sub >> 9, rn = sub & 511, rr = rn >> 7, n = rn & 127;
      const float* wr = fc_w + o * 640 + 128 + rr * 128;
      float acc = 0.f;
      for (int m = 0; m < 128; ++m) acc += wr[m] * sSM[m * 128 + n];
      FM[o * 512 + rn] = acc;
    }
  } else if (bid == 2561) {
    for (int e = tid; e < 512; e += 256) bias[e] = b_ih[e] + b_hh[e];
  } else if (bid < 2564) {
    int g = (bid - 2562) * 256 + tid;  // 0..511
    float acc = 0.f;
    for (int k = 0; k < 512; ++k) acc += rv0[k] * W_ih[(size_t)g * 768 + 256 + k];
    G0[g] = acc;
  } else {
    for (int e = tid; e < 4096; e += 256) slots[e] = 0u;  // 1024 wave-slots, 16B stride
  }
}

// ---------------------------------------------------------------------------
// persistent main: 256 blocks x 256 threads.
// Per-WAVE flags + dependency-only waits (128 specific wave-flags, not 256
// global blocks): producer wave signals right after its own vmcnt(0); skew
// between block groups is absorbed elastically. Dependency percolation
// reaches all blocks within 2 steps => 4 rotating h-buffers are race-free.
// ---------------------------------------------------------------------------
__global__ void __launch_bounds__(256, 1) dnc_main(
    const bf16* __restrict__ x_bf, const bf16* __restrict__ WMg,
    const float* __restrict__ bias, const float* __restrict__ G0,
    const float* __restrict__ FM, bf16* __restrict__ hbufs,
    float* __restrict__ hsumG, unsigned* __restrict__ slots,
    const float* __restrict__ W_ih, const float* __restrict__ W_hh,
    const float* __restrict__ fc_w, const float* __restrict__ fc_b,
    float* __restrict__ out) {
  __shared__ bf16 sWx[32][264];    // Wx  (32 owned gate cols) x K=256, odd granules
  __shared__ bf16 sWhh[32][136];
  __shared__ bf16 sWM[32][520];
  __shared__ bf16 sHq[16][520];    // hquad-major staged tile

  const int bid = blockIdx.x, tid = threadIdx.x;
  const int rt = bid >> 4, gt = bid & 15;
  const int wave = tid >> 6, lane = tid & 63;
  const int l15 = lane & 15, l4 = lane >> 4;

  auto gcol = [&](int pos) { return ((pos >> 3) << 7) + gt * 8 + (pos & 7); };

  // one-time weight staging into LDS
  for (int e = tid; e < 32 * 256; e += 256) sWx[e >> 8][e & 255] = (bf16)W_ih[(size_t)gcol(e >> 8) * 768 + (e & 255)];
  for (int e = tid; e < 32 * 128; e += 256) sWhh[e >> 7][e & 127] = (bf16)W_hh[gcol(e >> 7) * 128 + (e & 127)];
  for (int e = tid; e < 32 * 512; e += 256) sWM[e >> 9][e & 511] = WMg[(size_t)gcol(e >> 9) * 512 + (e & 511)];
  __syncthreads();

  const float bv0 = bias[gcol(l15)], bv1 = bias[gcol(16 + l15)];

  const bool lo = (l15 < 8);
  const int j = l15 & 7;
  const int rb = lo ? 0 : 2;
  float cst[2] = {0.f, 0.f}, hsum[2] = {0.f, 0.f};
  int growp[2];
#pragma unroll
  for (int k = 0; k < 2; ++k) growp[k] = rt * 16 + (l4 * 4 + rb + k) + 256 * wave;

  auto hb = [&](int t) { return hbufs + (size_t)(t & 3) * (BB * 128); };

  f32x4 acc0, acc1;

  auto xpart = [&](int t) {
    acc0 = f32x4{bv0, bv0, bv0, bv0};
    acc1 = f32x4{bv1, bv1, bv1, bv1};
    const bf16* xr = x_bf + ((size_t)t * BB + rt * 64 + wave * 16 + l15) * 256 + l4 * 8;
#pragma unroll
    for (int kk = 0; kk < 8; ++kk) {
      bf16x8 a  = *(const bf16x8*)(xr + kk * 32);
      bf16x8 w0 = *(const bf16x8*)&sWx[l15][kk * 32 + l4 * 8];
      bf16x8 w1 = *(const bf16x8*)&sWx[16 + l15][kk * 32 + l4 * 8];
      acc0 = __builtin_amdgcn_mfma_f32_16x16x32_bf16(a, w0, acc0, 0, 0, 0);
      acc1 = __builtin_amdgcn_mfma_f32_16x16x32_bf16(a, w1, acc1, 0, 0, 0);
    }
  };

  auto hpart = [&](const bf16* hrd) {
    // Whh A-rows into registers first (critical for early MFMA issue)
    bf16x8 ha[4];
    const bf16* hr = hrd + (size_t)(rt * 16 + l15 + 256 * wave) * 128 + l4 * 8;
#pragma unroll
    for (int kk = 0; kk < 4; ++kk) ha[kk] = ld_bf16x8_coh(hr + kk * 32);
    // stage h rows rt*64..+64 as hquad-major tile (row j holds h rows 4j..4j+3)
    // (prev-step sHq readers are separated from these writes by waitdeps' barrier)
#pragma unroll
    for (int pass = 0; pass < 4; ++pass) {
      int row = (tid >> 4) + 16 * pass, seg = tid & 15;
      bf16x8 v = ld_bf16x8_coh(hrd + (size_t)(rt * 64 + row) * 128 + seg * 8);
      *(bf16x8*)&sHq[row >> 2][(row & 3) * 128 + seg * 8] = v;
    }
#pragma unroll
    for (int kk = 0; kk < 4; ++kk) {
      bf16x8 w0 = *(const bf16x8*)&sWhh[l15][kk * 32 + l4 * 8];
      bf16x8 w1 = *(const bf16x8*)&sWhh[16 + l15][kk * 32 + l4 * 8];
      acc0 = __builtin_amdgcn_mfma_f32_16x16x32_bf16(ha[kk], w0, acc0, 0, 0, 0);
      acc1 = __builtin_amdgcn_mfma_f32_16x16x32_bf16(ha[kk], w1, acc1, 0, 0, 0);
    }
    __syncthreads();  // sHq ready
#pragma unroll
    for (int kk = 0; kk < 16; ++kk) {
      bf16x8 a  = *(const bf16x8*)&sHq[l15][kk * 32 + l4 * 8];
      bf16x8 w0 = *(const bf16x8*)&sWM[l15][kk * 32 + l4 * 8];
      bf16x8 w1 = *(const bf16x8*)&sWM[16 + l15][kk * 32 + l4 * 8];
      acc0 = __builtin_amdgcn_mfma_f32_16x16x32_bf16(a, w0, acc0, 0, 0, 0);
      acc1 = __builtin_amdgcn_mfma_f32_16x16x32_bf16(a, w1, acc1, 0, 0, 0);
    }
  };

  auto pw = [&](bool add_g0, bf16* hwr) {
    float o0[4], o1[4];
#pragma unroll
    for (int r = 0; r < 4; ++r) {
      o0[r] = __shfl_xor(acc0[r], 8);
      o1[r] = __shfl_xor(acc1[r], 8);
    }
    float g0i = 0.f, g0f = 0.f, g0g = 0.f, g0o = 0.f;
    if (add_g0) {
      int cb = gt * 8 + j;
      g0i = G0[cb]; g0f = G0[128 + cb]; g0g = G0[256 + cb]; g0o = G0[384 + cb];
    }
#pragma unroll
    for (int k = 0; k < 2; ++k) {
      int r = rb + k;
      float gi = (lo ? acc0[r] : o0[r]) + g0i;
      float gf = (lo ? o0[r] : acc0[r]) + g0f;
      float gg = (lo ? acc1[r] : o1[r]) + g0g;
      float go = (lo ? o1[r] : acc1[r]) + g0o;
      cst[k] = fsig(gf) * cst[k] + fsig(gi) * ftanh(gg);
      float h = fsig(go) * ftanh(cst[k]);
      hsum[k] += h;
      union { bf16 b; unsigned short u; } cv; cv.b = (bf16)h;
      st_u16_coh((unsigned short*)(hwr + (size_t)growp[k] * 128 + gt * 8 + j), cv.u);
    }
  };

  // per-WAVE signal: drain own stores, then lane 0 publishes. No block barrier.
  auto signal = [&](unsigned gen) {
    asm volatile("s_waitcnt vmcnt(0)" ::: "memory");
    if (lane == 0) st_u32_coh(slots + (bid * 4 + wave) * 4, gen);
  };
  // dependency-only wait: 128 wave-flags.
  //  tid<64 : Whh producers — wave (tid>>4) of block (rt*16 + (tid&15))
  //  64..127: hquad producers — wave (rt>>2) of block ((4*(rt&3)+((tid>>4)&3))*16 + (tid&15))
  auto waitdeps = [&](unsigned gen) {
    if (tid < 128) {
      int s;
      if (tid < 64) s = (rt * 16 + (tid & 15)) * 4 + (tid >> 4);
      else          s = ((4 * (rt & 3) + ((tid >> 4) & 3)) * 16 + (tid & 15)) * 4 + (rt >> 2);
      while (ld_u32_coh(slots + s * 4) < gen) {}
    }
    __syncthreads();
  };

  // ---- timeline: elastic dependency-driven pipeline, 4 rotating h-buffers --
  xpart(0);
  pw(true, hb(0));   // h_0 -> buf 0 (h(-1)=0; G-path = G0)
  signal(1);
  for (int t = 1; t < TT; ++t) {
    xpart(t);                              // h-independent, overlaps stragglers
    waitdeps(t);                           // only the 128 wave-flags we consume
    hpart(hb(t - 1));
    pw(false, hb(t));
    signal(t + 1);
  }
  // epilogue: hsum -> global, one-time all-wave wait, fused mean+projection
#pragma unroll
  for (int k = 0; k < 2; ++k)
    st_f32_coh(hsumG + (size_t)growp[k] * 128 + gt * 8 + j, hsum[k]);
  signal(TT + 2);
  for (int k = tid; k < 1024; k += 256)
    while (ld_u32_coh(slots + k * 4) < TT + 2) {}
  __syncthreads();
  {
    int row = bid * 4 + wave;
    const float* hsr = hsumG + (size_t)row * 128;
    const float* hqr = hsumG + (size_t)(row & 255) * 512;
    float s0 = 0.f, s1 = 0.f;
    for (int k = lane; k < 128; k += 64) { float v = ld_f32_coh(hsr + k); s0 += v * fc_w[k]; s1 += v * fc_w[640 + k]; }
    for (int k = lane; k < 512; k += 64) { float v = ld_f32_coh(hqr + k); s0 += v * FM[k]; s1 += v * FM[512 + k]; }
    for (int off = 32; off > 0; off >>= 1) { s0 += __shfl_down(s0, off); s1 += __shfl_down(s1, off); }
    if (lane == 0) {
      out[row * 2 + 0] = s0 * (1.f / 128.f) + fc_b[0];
      out[row * 2 + 1] = s1 * (1.f / 128.f) + fc_b[1];
    }
  }
}

// ---------------------------------------------------------------------------
extern "C" void kernel_launch(void* const* d_in, const int* in_sizes, int n_in,
                              void* d_out, int out_size, void* d_ws, size_t ws_size,
                              hipStream_t stream) {
  const float* x      = (const float*)d_in[0];
  const float* memory = (const float*)d_in[1];
  const float* rv0    = (const float*)d_in[2];
  const float* W_ih   = (const float*)d_in[3];
  const float* W_hh   = (const float*)d_in[4];
  const float* b_ih   = (const float*)d_in[5];
  const float* b_hh   = (const float*)d_in[6];
  const float* fc_w   = (const float*)d_in[7];
  const float* fc_b   = (const float*)d_in[8];
  float* out = (float*)d_out;
  char* ws = (char*)d_ws;

  bf16*     x_bf   = (bf16*)ws;                     // 67,108,864 B
  bf16*     WMg    = (bf16*)(ws + 67108864);        //    524,288
  // (gap: 65,536 B, unused)
  float*    bias   = (float*)(ws + 67698688);       //      2,048
  float*    G0     = (float*)(ws + 67700736);       //      2,048
  float*    FM     = (float*)(ws + 67702784);       //      4,096
  bf16*     hbufs  = (bf16*)(ws + 67706880);        //  1,048,576  (4 rotating bufs)
  unsigned* slots  = (unsigned*)(ws + 68755456);    //     16,384  (1024 wave-slots)
  float*    hsumG  = (float*)ws;                    // aliases x_bf t=0 slice (524,288 B)
  // hsumG alias safety: a block writes hsumG only after passing waitdeps(127),
  // which implies every block is past step 125 => x_bf slices 0..125 dead.

  prep<<<2565, 256, 0, stream>>>(x, memory, b_ih, b_hh, rv0, W_ih, fc_w,
                                 x_bf, WMg, bias, G0, FM, slots);
  dnc_main<<<NBLK, 256, 0, stream>>>(x_bf, WMg, bias, G0, FM, hbufs, hsumG, slots,
                                     W_ih, W_hh, fc_w, fc_b, out);
}

// Round 3
// 790.756 us; speedup vs baseline: 1.1690x; 1.1690x over previous
//
#include <hip/hip_runtime.h>

#define BB 1024
#define TT 128
#define NBLK 256

using bf16   = __bf16;
using bf16x8 = __attribute__((ext_vector_type(8))) bf16;
using bf16x4 = __attribute__((ext_vector_type(4))) bf16;
using f32x4  = __attribute__((ext_vector_type(4))) float;

__device__ __forceinline__ float fsig(float x) {
  return __builtin_amdgcn_rcpf(1.f + __expf(-x));
}
__device__ __forceinline__ float ftanh(float x) {
  return 2.f * __builtin_amdgcn_rcpf(1.f + __expf(-2.f * x)) - 1.f;
}

// ---- coherent (cross-XCD, IF$-served) load/store helpers -------------------
__device__ __forceinline__ void st_u32_coh(unsigned* p, unsigned v) {
  __hip_atomic_store(p, v, __ATOMIC_RELAXED, __HIP_MEMORY_SCOPE_AGENT);
}
__device__ __forceinline__ unsigned ld_u32_coh(const unsigned* p) {
  return __hip_atomic_load((unsigned*)p, __ATOMIC_RELAXED, __HIP_MEMORY_SCOPE_AGENT);
}
__device__ __forceinline__ float ld_f32_coh(const float* p) {
  return __hip_atomic_load((float*)p, __ATOMIC_RELAXED, __HIP_MEMORY_SCOPE_AGENT);
}
__device__ __forceinline__ void st_f32_coh(float* p, float v) {
  __hip_atomic_store(p, v, __ATOMIC_RELAXED, __HIP_MEMORY_SCOPE_AGENT);
}
__device__ __forceinline__ void st_u64_coh(unsigned long long* p, unsigned long long v) {
  __hip_atomic_store(p, v, __ATOMIC_RELAXED, __HIP_MEMORY_SCOPE_AGENT);
}
__device__ __forceinline__ bf16x8 ld_bf16x8_coh(const bf16* p) {
  union { unsigned long long u[2]; bf16x8 v; } c;
  c.u[0] = __hip_atomic_load((unsigned long long*)p, __ATOMIC_RELAXED, __HIP_MEMORY_SCOPE_AGENT);
  c.u[1] = __hip_atomic_load((unsigned long long*)(p + 4), __ATOMIC_RELAXED, __HIP_MEMORY_SCOPE_AGENT);
  return c.v;
}

// ---------------------------------------------------------------------------
// prep_a: x f32 [B,T,256] -> bf16 [T,row'(b),256] (2048 blocks), softmax,
//         bias, G0, zero slots    (identical to the proven round-0 version)
// ---------------------------------------------------------------------------
__global__ void prep_a(const float* __restrict__ x, const float* __restrict__ mem,
                       const float* __restrict__ b_ih, const float* __restrict__ b_hh,
                       const float* __restrict__ rv0, const float* __restrict__ W_ih,
                       bf16* __restrict__ x_bf, float* __restrict__ mem_sm,
                       float* __restrict__ bias, float* __restrict__ G0,
                       unsigned* __restrict__ slots) {
  const int bid = blockIdx.x, tid = threadIdx.x;
  if (bid < 2048) {
    const int lane = tid & 63, wv = tid >> 6;
    const int wg = bid * 4 + wv;  // 0..8191
#pragma unroll 4
    for (int r = 0; r < 16; ++r) {
      int rid = wg + r * 8192;            // rid = b*T + t
      int b = rid >> 7, t = rid & 127;
      int rowp = ((b >> 4) & 15) * 64 + (b >> 8) * 16 + (b & 15);
      const float4 v = *(const float4*)(x + (size_t)rid * 256 + lane * 4);
      bf16x4 o;
      o[0] = (bf16)v.x; o[1] = (bf16)v.y; o[2] = (bf16)v.z; o[3] = (bf16)v.w;
      *(bf16x4*)(x_bf + ((size_t)t * BB + rowp) * 256 + lane * 4) = o;
    }
  } else if (bid == 2048) {
    __shared__ float sM[128 * 128];
    for (int e = tid; e < 16384; e += 256) sM[e] = mem[e];
    __syncthreads();
    if (tid < 128) {
      float mx = -1e30f;
      for (int m = 0; m < 128; ++m) mx = fmaxf(mx, sM[m * 128 + tid]);
      float s = 0.f;
      for (int m = 0; m < 128; ++m) s += __expf(sM[m * 128 + tid] - mx);
      float inv = 1.f / s;
      for (int m = 0; m < 128; ++m) mem_sm[m * 128 + tid] = __expf(sM[m * 128 + tid] - mx) * inv;
    }
  } else if (bid == 2049) {
    for (int e = tid; e < 512; e += 256) bias[e] = b_ih[e] + b_hh[e];
  } else if (bid < 2052) {
    int g = (bid - 2050) * 256 + tid;  // 0..511
    float acc = 0.f;
    for (int k = 0; k < 512; ++k) acc += rv0[k] * W_ih[(size_t)g * 768 + 256 + k];
    G0[g] = acc;
  } else {
    for (int e = tid; e < 4096; e += 256) slots[e] = 0u;
  }
}

// ---------------------------------------------------------------------------
// prep_b: WM[g][r*128+n] = sum_m W_ih[g][256+r*128+m]*mem_sm[m][n]  (512 blocks)
//         FM (block 512)   (identical to round 0)
// ---------------------------------------------------------------------------
__global__ void prep_b(const float* __restrict__ W_ih, const float* __restrict__ fc_w,
                       const float* __restrict__ mem_sm,
                       bf16* __restrict__ WMg, float* __restrict__ FM) {
  const int bid = blockIdx.x, tid = threadIdx.x;
  if (bid < 512) {
    __shared__ float sW[512];
    const int g = bid;
    for (int e = tid; e < 512; e += 256) sW[e] = W_ih[(size_t)g * 768 + 256 + e];
    __syncthreads();
    const int r = tid >> 6, n0 = (tid & 63) * 2;
    float a0 = 0.f, a1 = 0.f;
    const float* wr = sW + r * 128;
#pragma unroll 4
    for (int m = 0; m < 128; ++m) {
      float2 ms = *(const float2*)(mem_sm + m * 128 + n0);
      a0 += wr[m] * ms.x;
      a1 += wr[m] * ms.y;
    }
    union { bf16 h[2]; unsigned u; } pk;
    pk.h[0] = (bf16)a0; pk.h[1] = (bf16)a1;
    *(unsigned*)(WMg + (size_t)g * 512 + r * 128 + n0) = pk.u;
  } else {
    for (int sub = tid; sub < 2 * 512; sub += 256) {
      int o = sub >> 9, rn = sub & 511, rr = rn >> 7, n = rn & 127;
      const float* wr = fc_w + o * 640 + 128 + rr * 128;
      float acc = 0.f;
      for (int m = 0; m < 128; ++m) acc += wr[m] * mem_sm[m * 128 + n];
      FM[o * 512 + rn] = acc;
    }
  }
}

// ---------------------------------------------------------------------------
// persistent main: 256 blocks x 256 threads, round-0 barrier scheme, but h is
// stored BLOCK-MAJOR: hG[gt][row][8] bf16, so every producer store and every
// consumer load is a coalesced 256B wave-burst instead of scattered 2B/8B
// transactions (the round-0/2 coherence-point throughput bottleneck).
// ---------------------------------------------------------------------------
__global__ void __launch_bounds__(256, 1) dnc_main(
    const bf16* __restrict__ x_bf, const bf16* __restrict__ WMg,
    const float* __restrict__ bias, const float* __restrict__ G0,
    const float* __restrict__ FM, bf16* __restrict__ hbuf0, bf16* __restrict__ hbuf1,
    float* __restrict__ hsumG, unsigned* __restrict__ slots,
    const float* __restrict__ W_ih, const float* __restrict__ W_hh,
    const float* __restrict__ fc_w, const float* __restrict__ fc_b,
    float* __restrict__ out) {
  __shared__ bf16 sWx[32][264];    // Wx  (32 owned gate cols) x K=256, odd granules
  __shared__ bf16 sWhh[32][136];
  __shared__ bf16 sWM[32][520];
  __shared__ bf16 sHq[16][520];    // hquad-major staged tile (layout unchanged)
  __shared__ unsigned short sStage[4][16][8];  // per-wave h pack tile (256B/wave)

  const int bid = blockIdx.x, tid = threadIdx.x;
  const int rt = bid >> 4, gt = bid & 15;
  const int wave = tid >> 6, lane = tid & 63;
  const int l15 = lane & 15, l4 = lane >> 4;

  auto gcol = [&](int pos) { return ((pos >> 3) << 7) + gt * 8 + (pos & 7); };

  // one-time weight staging into LDS
  for (int e = tid; e < 32 * 256; e += 256) sWx[e >> 8][e & 255] = (bf16)W_ih[(size_t)gcol(e >> 8) * 768 + (e & 255)];
  for (int e = tid; e < 32 * 128; e += 256) sWhh[e >> 7][e & 127] = (bf16)W_hh[gcol(e >> 7) * 128 + (e & 127)];
  for (int e = tid; e < 32 * 512; e += 256) sWM[e >> 9][e & 511] = WMg[(size_t)gcol(e >> 9) * 512 + (e & 511)];
  __syncthreads();

  const float bv0 = bias[gcol(l15)], bv1 = bias[gcol(16 + l15)];

  // pointwise cell ownership (register layout): lane(l4, j) j<8 -> rows l4*4+{0,1};
  // lane(l4, j+8) -> rows l4*4+{2,3}; col = gt*8+j; tile = wave.
  const bool lo = (l15 < 8);
  const int j = l15 & 7;
  const int rb = lo ? 0 : 2;
  float cst[2] = {0.f, 0.f}, hsum[2] = {0.f, 0.f};
  int growp[2];
#pragma unroll
  for (int k = 0; k < 2; ++k) growp[k] = rt * 16 + (l4 * 4 + rb + k) + 256 * wave;

  f32x4 acc0, acc1;

  auto xpart = [&](int t) {
    acc0 = f32x4{bv0, bv0, bv0, bv0};
    acc1 = f32x4{bv1, bv1, bv1, bv1};
    const bf16* xr = x_bf + ((size_t)t * BB + rt * 64 + wave * 16 + l15) * 256 + l4 * 8;
#pragma unroll
    for (int kk = 0; kk < 8; ++kk) {
      bf16x8 a  = *(const bf16x8*)(xr + kk * 32);
      bf16x8 w0 = *(const bf16x8*)&sWx[l15][kk * 32 + l4 * 8];
      bf16x8 w1 = *(const bf16x8*)&sWx[16 + l15][kk * 32 + l4 * 8];
      acc0 = __builtin_amdgcn_mfma_f32_16x16x32_bf16(a, w0, acc0, 0, 0, 0);
      acc1 = __builtin_amdgcn_mfma_f32_16x16x32_bf16(a, w1, acc1, 0, 0, 0);
    }
  };

  // h layout: hG[gtIdx 0..15][row 0..1023][8 cols] bf16 (16B chunk per (gt,row))
  auto hpart = [&](const bf16* hrd) {
    // Whh A-rows: col range kk*32+l4*8 -> chunk gtIdx = kk*4+l4, own row.
    // Adjacent l15 lanes -> adjacent rows -> contiguous 256B per load.
    bf16x8 ha[4];
    const int myrow = rt * 16 + l15 + 256 * wave;
#pragma unroll
    for (int kk = 0; kk < 4; ++kk)
      ha[kk] = ld_bf16x8_coh(hrd + ((size_t)((kk * 4 + l4) * 1024 + myrow)) * 8);
    // stage h rows rt*64..+64 as hquad-major tile; lane mapping chosen so
    // adjacent lanes load contiguous chunks (row64 = lane&15 fastest).
#pragma unroll
    for (int p = 0; p < 4; ++p) {
      int row64 = (lane & 15) + 16 * p;
      int seg = (lane >> 4) + 4 * wave;
      bf16x8 v = ld_bf16x8_coh(hrd + ((size_t)(seg * 1024 + rt * 64 + row64)) * 8);
      *(bf16x8*)&sHq[row64 >> 2][(row64 & 3) * 128 + seg * 8] = v;
    }
#pragma unroll
    for (int kk = 0; kk < 4; ++kk) {
      bf16x8 w0 = *(const bf16x8*)&sWhh[l15][kk * 32 + l4 * 8];
      bf16x8 w1 = *(const bf16x8*)&sWhh[16 + l15][kk * 32 + l4 * 8];
      acc0 = __builtin_amdgcn_mfma_f32_16x16x32_bf16(ha[kk], w0, acc0, 0, 0, 0);
      acc1 = __builtin_amdgcn_mfma_f32_16x16x32_bf16(ha[kk], w1, acc1, 0, 0, 0);
    }
    __syncthreads();  // sHq ready
#pragma unroll
    for (int kk = 0; kk < 16; ++kk) {
      bf16x8 a  = *(const bf16x8*)&sHq[l15][kk * 32 + l4 * 8];
      bf16x8 w0 = *(const bf16x8*)&sWM[l15][kk * 32 + l4 * 8];
      bf16x8 w1 = *(const bf16x8*)&sWM[16 + l15][kk * 32 + l4 * 8];
      acc0 = __builtin_amdgcn_mfma_f32_16x16x32_bf16(a, w0, acc0, 0, 0, 0);
      acc1 = __builtin_amdgcn_mfma_f32_16x16x32_bf16(a, w1, acc1, 0, 0, 0);
    }
  };

  auto pw = [&](bool add_g0, bf16* hwr) {
    float o0[4], o1[4];
#pragma unroll
    for (int r = 0; r < 4; ++r) {
      o0[r] = __shfl_xor(acc0[r], 8);
      o1[r] = __shfl_xor(acc1[r], 8);
    }
    float g0i = 0.f, g0f = 0.f, g0g = 0.f, g0o = 0.f;
    if (add_g0) {
      int cb = gt * 8 + j;
      g0i = G0[cb]; g0f = G0[128 + cb]; g0g = G0[256 + cb]; g0o = G0[384 + cb];
    }
#pragma unroll
    for (int k = 0; k < 2; ++k) {
      int r = rb + k;
      float gi = (lo ? acc0[r] : o0[r]) + g0i;
      float gf = (lo ? o0[r] : acc0[r]) + g0f;
      float gg = (lo ? acc1[r] : o1[r]) + g0g;
      float go = (lo ? o1[r] : acc1[r]) + g0o;
      cst[k] = fsig(gf) * cst[k] + fsig(gi) * ftanh(gg);
      float h = fsig(go) * ftanh(cst[k]);
      hsum[k] += h;
      union { bf16 b; unsigned short u; } cv; cv.b = (bf16)h;
      sStage[wave][l4 * 4 + rb + k][j] = cv.u;  // wave-local pack tile
    }
    asm volatile("" ::: "memory");  // keep ds_write -> ds_read order (in-order LDS pipe)
    // pack-store: 32 lanes x u64 = one contiguous 256B burst per wave
    if (lane < 32) {
      unsigned long long v = *(const unsigned long long*)&sStage[wave][lane >> 1][(lane & 1) * 4];
      int row = rt * 16 + 256 * wave + (lane >> 1);
      st_u64_coh((unsigned long long*)((char*)hwr + ((size_t)(gt * 1024 + row)) * 16 + (lane & 1) * 8), v);
    }
  };

  auto commit = [&](unsigned gen) {
    asm volatile("s_waitcnt vmcnt(0)" ::: "memory");
    __syncthreads();
    if (tid == 0) st_u32_coh(slots + bid * 16, gen);
  };
  auto gridwait = [&](unsigned gen) {
    // single-hop all-to-all: thread t polls block t's slot
    while (ld_u32_coh(slots + tid * 16) < gen) {}
    __syncthreads();
  };

  // ---- timeline: one barrier per step, double-buffered h ------------------
  xpart(0);
  pw(true, hbuf0);   // h_0 -> buf0 (h(-1)=0; G-path = G0)
  commit(1);
  for (int t = 1; t < TT; ++t) {
    xpart(t);                              // h-independent, overlaps stragglers
    gridwait(t);                           // all blocks committed h_{t-1}
    hpart((t & 1) ? hbuf0 : hbuf1);        // read h_{t-1} from buf[(t-1)&1]
    pw(false, (t & 1) ? hbuf1 : hbuf0);    // write h_t to buf[t&1]
    commit(t + 1);
  }
  // epilogue: hsum -> global, barrier, fused mean+projection
#pragma unroll
  for (int k = 0; k < 2; ++k)
    st_f32_coh(hsumG + (size_t)growp[k] * 128 + gt * 8 + j, hsum[k]);
  commit(TT + 1);
  gridwait(TT + 1);
  {
    int row = bid * 4 + wave;
    const float* hsr = hsumG + (size_t)row * 128;
    const float* hqr = hsumG + (size_t)(row & 255) * 512;
    float s0 = 0.f, s1 = 0.f;
    for (int k = lane; k < 128; k += 64) { float v = ld_f32_coh(hsr + k); s0 += v * fc_w[k]; s1 += v * fc_w[640 + k]; }
    for (int k = lane; k < 512; k += 64) { float v = ld_f32_coh(hqr + k); s0 += v * FM[k]; s1 += v * FM[512 + k]; }
    for (int off = 32; off > 0; off >>= 1) { s0 += __shfl_down(s0, off); s1 += __shfl_down(s1, off); }
    if (lane == 0) {
      out[row * 2 + 0] = s0 * (1.f / 128.f) + fc_b[0];
      out[row * 2 + 1] = s1 * (1.f / 128.f) + fc_b[1];
    }
  }
}

// ---------------------------------------------------------------------------
extern "C" void kernel_launch(void* const* d_in, const int* in_sizes, int n_in,
                              void* d_out, int out_size, void* d_ws, size_t ws_size,
                              hipStream_t stream) {
  const float* x      = (const float*)d_in[0];
  const float* memory = (const float*)d_in[1];
  const float* rv0    = (const float*)d_in[2];
  const float* W_ih   = (const float*)d_in[3];
  const float* W_hh   = (const float*)d_in[4];
  const float* b_ih   = (const float*)d_in[5];
  const float* b_hh   = (const float*)d_in[6];
  const float* fc_w   = (const float*)d_in[7];
  const float* fc_b   = (const float*)d_in[8];
  float* out = (float*)d_out;
  char* ws = (char*)d_ws;

  bf16*     x_bf   = (bf16*)ws;                     // 67,108,864 B
  bf16*     WMg    = (bf16*)(ws + 67108864);        //    524,288
  float*    mem_sm = (float*)(ws + 67633152);       //     65,536
  float*    bias   = (float*)(ws + 67698688);       //      2,048
  float*    G0     = (float*)(ws + 67700736);       //      2,048
  float*    FM     = (float*)(ws + 67702784);       //      4,096
  bf16*     hbuf0  = (bf16*)(ws + 67706880);        //    262,144
  bf16*     hbuf1  = (bf16*)(ws + 67969024);        //    262,144
  unsigned* slots  = (unsigned*)(ws + 68231168);    //     16,384
  float*    hsumG  = (float*)(ws + 68247552);       //    524,288

  prep_a<<<2053, 256, 0, stream>>>(x, memory, b_ih, b_hh, rv0, W_ih,
                                   x_bf, mem_sm, bias, G0, slots);
  prep_b<<<513, 256, 0, stream>>>(W_ih, fc_w, mem_sm, WMg, FM);
  dnc_main<<<NBLK, 256, 0, stream>>>(x_bf, WMg, bias, G0, FM, hbuf0, hbuf1, hsumG, slots,
                                     W_ih, W_hh, fc_w, fc_b, out);
}

// Round 4
// 747.508 us; speedup vs baseline: 1.2367x; 1.0579x over previous
//
#include <hip/hip_runtime.h>

#define BB 1024
#define TT 128
#define NBLK 256
#define POISON64 0x7FC07FC07FC07FC0ULL

using bf16   = __bf16;
using bf16x8 = __attribute__((ext_vector_type(8))) bf16;
using bf16x4 = __attribute__((ext_vector_type(4))) bf16;
using f32x4  = __attribute__((ext_vector_type(4))) float;

__device__ __forceinline__ float fsig(float x) {
  return __builtin_amdgcn_rcpf(1.f + __expf(-x));
}
__device__ __forceinline__ float ftanh(float x) {
  return 2.f * __builtin_amdgcn_rcpf(1.f + __expf(-2.f * x)) - 1.f;
}

// ---- coherent (cross-XCD, IF$-served) load/store helpers -------------------
__device__ __forceinline__ void st_u32_coh(unsigned* p, unsigned v) {
  __hip_atomic_store(p, v, __ATOMIC_RELAXED, __HIP_MEMORY_SCOPE_AGENT);
}
__device__ __forceinline__ unsigned ld_u32_coh(const unsigned* p) {
  return __hip_atomic_load((unsigned*)p, __ATOMIC_RELAXED, __HIP_MEMORY_SCOPE_AGENT);
}
__device__ __forceinline__ float ld_f32_coh(const float* p) {
  return __hip_atomic_load((float*)p, __ATOMIC_RELAXED, __HIP_MEMORY_SCOPE_AGENT);
}
__device__ __forceinline__ void st_f32_coh(float* p, float v) {
  __hip_atomic_store(p, v, __ATOMIC_RELAXED, __HIP_MEMORY_SCOPE_AGENT);
}
__device__ __forceinline__ void st_u64_coh(unsigned long long* p, unsigned long long v) {
  __hip_atomic_store(p, v, __ATOMIC_RELAXED, __HIP_MEMORY_SCOPE_AGENT);
}
__device__ __forceinline__ unsigned long long ld_u64_coh(const unsigned long long* p) {
  return __hip_atomic_load((unsigned long long*)p, __ATOMIC_RELAXED, __HIP_MEMORY_SCOPE_AGENT);
}
// exact: nonzero iff some bf16 halfword of v equals POISON (0x7FC0)
__device__ __forceinline__ bool haspoison(unsigned long long v) {
  unsigned long long x = v ^ POISON64;
  return ((x - 0x0001000100010001ULL) & ~x & 0x8000800080008000ULL) != 0ULL;
}

// ---------------------------------------------------------------------------
// prep_a: x f32 [B,T,256] -> bf16 [T,row'(b),256] + poison hbufs (2048 blocks),
//         softmax, bias, G0, zero slots
// ---------------------------------------------------------------------------
__global__ void prep_a(const float* __restrict__ x, const float* __restrict__ mem,
                       const float* __restrict__ b_ih, const float* __restrict__ b_hh,
                       const float* __restrict__ rv0, const float* __restrict__ W_ih,
                       bf16* __restrict__ x_bf, bf16* __restrict__ hbufs,
                       float* __restrict__ mem_sm,
                       float* __restrict__ bias, float* __restrict__ G0,
                       unsigned* __restrict__ slots) {
  const int bid = blockIdx.x, tid = threadIdx.x;
  if (bid < 2048) {
    const int lane = tid & 63, wv = tid >> 6;
    const int wg = bid * 4 + wv;  // 0..8191
#pragma unroll 4
    for (int r = 0; r < 16; ++r) {
      int rid = wg + r * 8192;            // rid = b*T + t
      int b = rid >> 7, t = rid & 127;
      int rowp = ((b >> 4) & 15) * 64 + (b >> 8) * 16 + (b & 15);
      const float4 v = *(const float4*)(x + (size_t)rid * 256 + lane * 4);
      bf16x4 o;
      o[0] = (bf16)v.x; o[1] = (bf16)v.y; o[2] = (bf16)v.z; o[3] = (bf16)v.w;
      *(bf16x4*)(x_bf + ((size_t)t * BB + rowp) * 256 + lane * 4) = o;
    }
    // poison my 16 KB slice of the 33.5 MB h step-buffer arena
    char* pb = (char*)hbufs + (size_t)bid * 16384 + tid * 16;
#pragma unroll
    for (int ps = 0; ps < 4; ++ps) {
      unsigned long long* p = (unsigned long long*)(pb + ps * 4096);
      p[0] = POISON64; p[1] = POISON64;
    }
  } else if (bid == 2048) {
    __shared__ float sM[128 * 128];
    for (int e = tid; e < 16384; e += 256) sM[e] = mem[e];
    __syncthreads();
    if (tid < 128) {
      float mx = -1e30f;
      for (int m = 0; m < 128; ++m) mx = fmaxf(mx, sM[m * 128 + tid]);
      float s = 0.f;
      for (int m = 0; m < 128; ++m) s += __expf(sM[m * 128 + tid] - mx);
      float inv = 1.f / s;
      for (int m = 0; m < 128; ++m) mem_sm[m * 128 + tid] = __expf(sM[m * 128 + tid] - mx) * inv;
    }
  } else if (bid == 2049) {
    for (int e = tid; e < 512; e += 256) bias[e] = b_ih[e] + b_hh[e];
  } else if (bid < 2052) {
    int g = (bid - 2050) * 256 + tid;  // 0..511
    float acc = 0.f;
    for (int k = 0; k < 512; ++k) acc += rv0[k] * W_ih[(size_t)g * 768 + 256 + k];
    G0[g] = acc;
  } else {
    for (int e = tid; e < 4096; e += 256) slots[e] = 0u;
  }
}

// ---------------------------------------------------------------------------
// prep_b: WM[g][r*128+n] = sum_m W_ih[g][256+r*128+m]*mem_sm[m][n]  (512 blocks)
//         FM (block 512)
// ---------------------------------------------------------------------------
__global__ void prep_b(const float* __restrict__ W_ih, const float* __restrict__ fc_w,
                       const float* __restrict__ mem_sm,
                       bf16* __restrict__ WMg, float* __restrict__ FM) {
  const int bid = blockIdx.x, tid = threadIdx.x;
  if (bid < 512) {
    __shared__ float sW[512];
    const int g = bid;
    for (int e = tid; e < 512; e += 256) sW[e] = W_ih[(size_t)g * 768 + 256 + e];
    __syncthreads();
    const int r = tid >> 6, n0 = (tid & 63) * 2;
    float a0 = 0.f, a1 = 0.f;
    const float* wr = sW + r * 128;
#pragma unroll 4
    for (int m = 0; m < 128; ++m) {
      float2 ms = *(const float2*)(mem_sm + m * 128 + n0);
      a0 += wr[m] * ms.x;
      a1 += wr[m] * ms.y;
    }
    union { bf16 h[2]; unsigned u; } pk;
    pk.h[0] = (bf16)a0; pk.h[1] = (bf16)a1;
    *(unsigned*)(WMg + (size_t)g * 512 + r * 128 + n0) = pk.u;
  } else {
    for (int sub = tid; sub < 2 * 512; sub += 256) {
      int o = sub >> 9, rn = sub & 511, rr = rn >> 7, n = rn & 127;
      const float* wr = fc_w + o * 640 + 128 + rr * 128;
      float acc = 0.f;
      for (int m = 0; m < 128; ++m) acc += wr[m] * mem_sm[m * 128 + n];
      FM[o * 512 + rn] = acc;
    }
  }
}

// ---------------------------------------------------------------------------
// persistent main: 256 blocks x 256 threads. NO per-step barrier or flags:
// h_t -> private per-step buffer (pre-poisoned bf16 NaN; h is always finite so
// poison is unforgeable; write-once => no reuse races). Consumers poll exactly
// the 16 u64 chunks they need — the data IS the flag. Producer never waits.
// h layout stays R3's block-major hG[gt][row][8] (coalesced 256B bursts).
// ---------------------------------------------------------------------------
__global__ void __launch_bounds__(256, 1) dnc_main(
    const bf16* __restrict__ x_bf, const bf16* __restrict__ WMg,
    const float* __restrict__ bias, const float* __restrict__ G0,
    const float* __restrict__ FM, bf16* __restrict__ hbufs,
    float* __restrict__ hsumG, unsigned* __restrict__ slots,
    const float* __restrict__ W_ih, const float* __restrict__ W_hh,
    const float* __restrict__ fc_w, const float* __restrict__ fc_b,
    float* __restrict__ out) {
  __shared__ bf16 sWx[32][264];
  __shared__ bf16 sWhh[32][136];
  __shared__ bf16 sWM[32][520];
  __shared__ bf16 sHq[16][520];    // hquad-major staged tile
  __shared__ unsigned short sStage[4][16][8];  // per-wave h pack tile

  const int bid = blockIdx.x, tid = threadIdx.x;
  const int rt = bid >> 4, gt = bid & 15;
  const int wave = tid >> 6, lane = tid & 63;
  const int l15 = lane & 15, l4 = lane >> 4;

  auto gcol = [&](int pos) { return ((pos >> 3) << 7) + gt * 8 + (pos & 7); };

  // one-time weight staging into LDS
  for (int e = tid; e < 32 * 256; e += 256) sWx[e >> 8][e & 255] = (bf16)W_ih[(size_t)gcol(e >> 8) * 768 + (e & 255)];
  for (int e = tid; e < 32 * 128; e += 256) sWhh[e >> 7][e & 127] = (bf16)W_hh[gcol(e >> 7) * 128 + (e & 127)];
  for (int e = tid; e < 32 * 512; e += 256) sWM[e >> 9][e & 511] = WMg[(size_t)gcol(e >> 9) * 512 + (e & 511)];
  __syncthreads();

  const float bv0 = bias[gcol(l15)], bv1 = bias[gcol(16 + l15)];

  const bool lo = (l15 < 8);
  const int j = l15 & 7;
  const int rb = lo ? 0 : 2;
  float cst[2] = {0.f, 0.f}, hsum[2] = {0.f, 0.f};
  int growp[2];
#pragma unroll
  for (int k = 0; k < 2; ++k) growp[k] = rt * 16 + (l4 * 4 + rb + k) + 256 * wave;

  f32x4 acc0, acc1;

  auto xpart = [&](int t) {
    acc0 = f32x4{bv0, bv0, bv0, bv0};
    acc1 = f32x4{bv1, bv1, bv1, bv1};
    const bf16* xr = x_bf + ((size_t)t * BB + rt * 64 + wave * 16 + l15) * 256 + l4 * 8;
#pragma unroll
    for (int kk = 0; kk < 8; ++kk) {
      bf16x8 a  = *(const bf16x8*)(xr + kk * 32);
      bf16x8 w0 = *(const bf16x8*)&sWx[l15][kk * 32 + l4 * 8];
      bf16x8 w1 = *(const bf16x8*)&sWx[16 + l15][kk * 32 + l4 * 8];
      acc0 = __builtin_amdgcn_mfma_f32_16x16x32_bf16(a, w0, acc0, 0, 0, 0);
      acc1 = __builtin_amdgcn_mfma_f32_16x16x32_bf16(a, w1, acc1, 0, 0, 0);
    }
  };

  // h layout: hG[gtIdx 0..15][row 0..1023][8 cols] bf16 (16B chunk per (gt,row))
  auto hpart = [&](const bf16* hrd) {
    const unsigned long long* hb64 = (const unsigned long long*)hrd;
    const int myrow = rt * 16 + l15 + 256 * wave;
    const int seg = (lane >> 4) + 4 * wave;
    int ia[4], ist[4];
#pragma unroll
    for (int kk = 0; kk < 4; ++kk) ia[kk] = ((kk * 4 + l4) * 1024 + myrow) * 2;
#pragma unroll
    for (int p = 0; p < 4; ++p) ist[p] = (seg * 1024 + rt * 64 + (lane & 15) + 16 * p) * 2;
    // issue all 16 u64 loads batched (independent)
    unsigned long long va[8], vs[8];
#pragma unroll
    for (int kk = 0; kk < 4; ++kk) {
      va[2 * kk]     = ld_u64_coh(hb64 + ia[kk]);
      va[2 * kk + 1] = ld_u64_coh(hb64 + ia[kk] + 1);
    }
#pragma unroll
    for (int p = 0; p < 4; ++p) {
      vs[2 * p]     = ld_u64_coh(hb64 + ist[p]);
      vs[2 * p + 1] = ld_u64_coh(hb64 + ist[p] + 1);
    }
    // phase 1: complete Whh chunks (write-once => non-poison observation is final)
    for (;;) {
      unsigned st = 0;
#pragma unroll
      for (int i = 0; i < 8; ++i) st |= haspoison(va[i]) ? (1u << i) : 0u;
      if (!st) break;
      __builtin_amdgcn_s_sleep(1);
#pragma unroll
      for (int i = 0; i < 8; ++i)
        if (st & (1u << i)) va[i] = ld_u64_coh(hb64 + ia[i >> 1] + (i & 1));
    }
#pragma unroll
    for (int kk = 0; kk < 4; ++kk) {
      union { unsigned long long u[2]; bf16x8 b; } c;
      c.u[0] = va[2 * kk]; c.u[1] = va[2 * kk + 1];
      bf16x8 w0 = *(const bf16x8*)&sWhh[l15][kk * 32 + l4 * 8];
      bf16x8 w1 = *(const bf16x8*)&sWhh[16 + l15][kk * 32 + l4 * 8];
      acc0 = __builtin_amdgcn_mfma_f32_16x16x32_bf16(c.b, w0, acc0, 0, 0, 0);
      acc1 = __builtin_amdgcn_mfma_f32_16x16x32_bf16(c.b, w1, acc1, 0, 0, 0);
    }
    __syncthreads();  // all waves done reading prev-step sHq
    // phase 2: complete staging chunks, build sHq
    for (;;) {
      unsigned st = 0;
#pragma unroll
      for (int i = 0; i < 8; ++i) st |= haspoison(vs[i]) ? (1u << i) : 0u;
      if (!st) break;
      __builtin_amdgcn_s_sleep(1);
#pragma unroll
      for (int i = 0; i < 8; ++i)
        if (st & (1u << i)) vs[i] = ld_u64_coh(hb64 + ist[i >> 1] + (i & 1));
    }
#pragma unroll
    for (int p = 0; p < 4; ++p) {
      int row64 = (lane & 15) + 16 * p;
      union { unsigned long long u[2]; bf16x8 b; } c;
      c.u[0] = vs[2 * p]; c.u[1] = vs[2 * p + 1];
      *(bf16x8*)&sHq[row64 >> 2][(row64 & 3) * 128 + seg * 8] = c.b;
    }
    __syncthreads();  // sHq ready
#pragma unroll
    for (int kk = 0; kk < 16; ++kk) {
      bf16x8 a  = *(const bf16x8*)&sHq[l15][kk * 32 + l4 * 8];
      bf16x8 w0 = *(const bf16x8*)&sWM[l15][kk * 32 + l4 * 8];
      bf16x8 w1 = *(const bf16x8*)&sWM[16 + l15][kk * 32 + l4 * 8];
      acc0 = __builtin_amdgcn_mfma_f32_16x16x32_bf16(a, w0, acc0, 0, 0, 0);
      acc1 = __builtin_amdgcn_mfma_f32_16x16x32_bf16(a, w1, acc1, 0, 0, 0);
    }
  };

  auto pw = [&](bool add_g0, bf16* hwr) {
    float o0[4], o1[4];
#pragma unroll
    for (int r = 0; r < 4; ++r) {
      o0[r] = __shfl_xor(acc0[r], 8);
      o1[r] = __shfl_xor(acc1[r], 8);
    }
    float g0i = 0.f, g0f = 0.f, g0g = 0.f, g0o = 0.f;
    if (add_g0) {
      int cb = gt * 8 + j;
      g0i = G0[cb]; g0f = G0[128 + cb]; g0g = G0[256 + cb]; g0o = G0[384 + cb];
    }
#pragma unroll
    for (int k = 0; k < 2; ++k) {
      int r = rb + k;
      float gi = (lo ? acc0[r] : o0[r]) + g0i;
      float gf = (lo ? o0[r] : acc0[r]) + g0f;
      float gg = (lo ? acc1[r] : o1[r]) + g0g;
      float go = (lo ? o1[r] : acc1[r]) + g0o;
      cst[k] = fsig(gf) * cst[k] + fsig(gi) * ftanh(gg);
      float h = fsig(go) * ftanh(cst[k]);
      hsum[k] += h;
      union { bf16 b; unsigned short u; } cv; cv.b = (bf16)h;
      sStage[wave][l4 * 4 + rb + k][j] = cv.u;  // wave-local pack tile
    }
    asm volatile("" ::: "memory");  // keep ds_write -> ds_read order (in-order per wave)
    // pack-store: 32 lanes x u64 = one contiguous 256B burst per wave; no wait after
    if (lane < 32) {
      unsigned long long v = *(const unsigned long long*)&sStage[wave][lane >> 1][(lane & 1) * 4];
      int row = rt * 16 + 256 * wave + (lane >> 1);
      st_u64_coh((unsigned long long*)((char*)hwr + ((size_t)(gt * 1024 + row)) * 16 + (lane & 1) * 8), v);
    }
  };

  // ---- timeline: fully elastic; producer never waits ----------------------
  xpart(0);
  pw(true, hbufs);                                   // h_0 -> buf 0
  for (int t = 1; t < TT; ++t) {
    xpart(t);                                        // h-independent overlap
    hpart(hbufs + (size_t)(t - 1) * (16 * 1024 * 8));// polls h_{t-1}
    pw(false, hbufs + (size_t)t * (16 * 1024 * 8));  // writes h_t, no drain
  }
  // epilogue: hsum -> global, one-shot slot barrier, fused mean+projection
#pragma unroll
  for (int k = 0; k < 2; ++k)
    st_f32_coh(hsumG + (size_t)growp[k] * 128 + gt * 8 + j, hsum[k]);
  asm volatile("s_waitcnt vmcnt(0)" ::: "memory");
  __syncthreads();
  if (tid == 0) st_u32_coh(slots + bid * 16, 1u);
  while (ld_u32_coh(slots + tid * 16) < 1u) {}
  __syncthreads();
  {
    int row = bid * 4 + wave;
    const float* hsr = hsumG + (size_t)row * 128;
    const float* hqr = hsumG + (size_t)(row & 255) * 512;
    float s0 = 0.f, s1 = 0.f;
    for (int k = lane; k < 128; k += 64) { float v = ld_f32_coh(hsr + k); s0 += v * fc_w[k]; s1 += v * fc_w[640 + k]; }
    for (int k = lane; k < 512; k += 64) { float v = ld_f32_coh(hqr + k); s0 += v * FM[k]; s1 += v * FM[512 + k]; }
    for (int off = 32; off > 0; off >>= 1) { s0 += __shfl_down(s0, off); s1 += __shfl_down(s1, off); }
    if (lane == 0) {
      out[row * 2 + 0] = s0 * (1.f / 128.f) + fc_b[0];
      out[row * 2 + 1] = s1 * (1.f / 128.f) + fc_b[1];
    }
  }
}

// ---------------------------------------------------------------------------
extern "C" void kernel_launch(void* const* d_in, const int* in_sizes, int n_in,
                              void* d_out, int out_size, void* d_ws, size_t ws_size,
                              hipStream_t stream) {
  const float* x      = (const float*)d_in[0];
  const float* memory = (const float*)d_in[1];
  const float* rv0    = (const float*)d_in[2];
  const float* W_ih   = (const float*)d_in[3];
  const float* W_hh   = (const float*)d_in[4];
  const float* b_ih   = (const float*)d_in[5];
  const float* b_hh   = (const float*)d_in[6];
  const float* fc_w   = (const float*)d_in[7];
  const float* fc_b   = (const float*)d_in[8];
  float* out = (float*)d_out;
  char* ws = (char*)d_ws;

  bf16*     x_bf   = (bf16*)ws;                     // 67,108,864
  bf16*     WMg    = (bf16*)(ws + 67108864);        //    524,288
  float*    mem_sm = (float*)(ws + 67633152);       //     65,536
  float*    bias   = (float*)(ws + 67698688);       //      2,048
  float*    G0     = (float*)(ws + 67700736);       //      2,048
  float*    FM     = (float*)(ws + 67702784);       //      4,096
  unsigned* slots  = (unsigned*)(ws + 67706880);    //     16,384
  float*    hsumG  = (float*)(ws + 67723264);       //    524,288
  bf16*     hbufs  = (bf16*)(ws + 68247552);        // 33,554,432 (128 step bufs, end 101,801,984)

  prep_a<<<2053, 256, 0, stream>>>(x, memory, b_ih, b_hh, rv0, W_ih,
                                   x_bf, hbufs, mem_sm, bias, G0, slots);
  prep_b<<<513, 256, 0, stream>>>(W_ih, fc_w, mem_sm, WMg, FM);
  dnc_main<<<NBLK, 256, 0, stream>>>(x_bf, WMg, bias, G0, FM, hbufs, hsumG, slots,
                                     W_ih, W_hh, fc_w, fc_b, out);
}